// Round 4
// baseline (498.767 us; speedup 1.0000x reference)
//
#include <hip/hip_runtime.h>
#include <stdint.h>

#define M_DIM 8192
#define N_DIM 8192
#define K_DIM 64
#define PANEL_M 16      // output rows per block
#define SPAN_N 256      // output cols per wave
#define BLOCK_N 1024    // cols per block (4 waves)

typedef __attribute__((ext_vector_type(8))) short short8;   // 8 bf16 = 4 VGPRs
typedef __attribute__((ext_vector_type(4))) float f32x4;

__device__ __forceinline__ ushort f2bf(float f) {
    // round-to-nearest-even fp32 -> bf16 (inputs finite)
    uint u = __float_as_uint(f);
    return (ushort)((u + 0x7FFFu + ((u >> 16) & 1u)) >> 16);
}

// z [64,N] fp32 -> zt [N,64] bf16 (transpose). Verified in R0.
// block = 64 cols x 4 k-chunks of 16. Reads coalesced (256B/instr). 128 blocks.
__global__ __launch_bounds__(256) void prep_zt(const float* __restrict__ z,
                                               ushort* __restrict__ zt) {
    int n  = blockIdx.x * 64 + (threadIdx.x & 63);
    int k0 = (threadIdx.x >> 6) * 16;
    uint w[8];
#pragma unroll
    for (int j = 0; j < 8; ++j) {
        ushort a = f2bf(z[(size_t)(k0 + 2 * j) * N_DIM + n]);
        ushort b = f2bf(z[(size_t)(k0 + 2 * j + 1) * N_DIM + n]);
        w[j] = (uint)a | ((uint)b << 16);
    }
    uint4* dst = (uint4*)(zt + (size_t)n * 64 + k0);
    dst[0] = make_uint4(w[0], w[1], w[2], w[3]);
    dst[1] = make_uint4(w[4], w[5], w[6], w[7]);
}

// Swapped-operand streaming main: zero LDS, zero barriers.
// D = A*B with A = zt tile (A[row=n_local=l&15][k]) and B = y^T
// (B[k][col=m_local=l&15]) -- the SAME per-lane loads as the verified R0
// kernel, only the MFMA argument order swaps. C layout (col=l&15,
// row=(l>>4)*4+reg, HW-verified) then means lane l's 4 acc regs are
// out[m0+(l&15)][ntile+4*(l>>4) + 0..3] -- one aligned f32x4, fused with
// the x multiply and stored directly (no LDS re-layout pass).
// Per wave-instruction: 16 rows x 64B; consecutive tiles cover adjacent
// 64B halves so all 128B lines are fully consumed (reads) / dirtied (writes).
__global__ __launch_bounds__(256) void sddmm_rows(const float* __restrict__ x,
                                                  const float* __restrict__ y,
                                                  const ushort* __restrict__ zt,
                                                  float* __restrict__ out) {
    const int tid = threadIdx.x;
    const int wv  = tid >> 6;   // wave 0..3
    const int l   = tid & 63;
    const int q   = l >> 4;     // 0..3
    const int r16 = l & 15;     // 0..15
    const int m0  = blockIdx.y * PANEL_M;
    const int nw  = blockIdx.x * BLOCK_N + wv * SPAN_N;

    // B-operand frags from y (fp32 -> bf16 in-register, k-contiguous),
    // converted once per wave, reused for all 16 n-tiles. L2-resident.
    short8 by[2];
#pragma unroll
    for (int kc = 0; kc < 2; ++kc) {
        const float* yp = y + (size_t)(m0 + r16) * K_DIM + 32 * kc + 8 * q;
        float4 v0 = *(const float4*)(yp);
        float4 v1 = *(const float4*)(yp + 4);
        union { uint u[4]; short8 s; } fr;
        fr.u[0] = (uint)f2bf(v0.x) | ((uint)f2bf(v0.y) << 16);
        fr.u[1] = (uint)f2bf(v0.z) | ((uint)f2bf(v0.w) << 16);
        fr.u[2] = (uint)f2bf(v1.x) | ((uint)f2bf(v1.y) << 16);
        fr.u[3] = (uint)f2bf(v1.z) | ((uint)f2bf(v1.w) << 16);
        by[kc] = fr.s;
    }

    // A-frag base: zt[(nw + r16)][8q ...], tile t adds 16t rows, kc adds 32.
    const ushort* za  = zt + (size_t)(nw + r16) * K_DIM + 8 * q;
    // x/out base: [m0 + r16][nw + 4q ...], tile t adds 16t.
    const size_t xoff = (size_t)(m0 + r16) * N_DIM + nw + 4 * q;

#pragma unroll 2
    for (int t = 0; t < SPAN_N / 16; t += 2) {
        const size_t xo0 = xoff + 16 * t;
        const size_t xo1 = xo0 + 16;
        // x streams: non-temporal (no reuse; keep zt/y L2-resident)
        f32x4 xv0 = __builtin_nontemporal_load((const f32x4*)(x + xo0));
        f32x4 xv1 = __builtin_nontemporal_load((const f32x4*)(x + xo1));

        const ushort* z0 = za + (size_t)(16 * t) * K_DIM;
        const ushort* z1 = z0 + 16 * K_DIM;
        short8 a00 = *(const short8*)(z0);        // kc=0
        short8 a01 = *(const short8*)(z0 + 32);   // kc=1
        short8 a10 = *(const short8*)(z1);
        short8 a11 = *(const short8*)(z1 + 32);

        f32x4 acc0 = {}, acc1 = {};
        acc0 = __builtin_amdgcn_mfma_f32_16x16x32_bf16(a00, by[0], acc0, 0, 0, 0);
        acc0 = __builtin_amdgcn_mfma_f32_16x16x32_bf16(a01, by[1], acc0, 0, 0, 0);
        acc1 = __builtin_amdgcn_mfma_f32_16x16x32_bf16(a10, by[0], acc1, 0, 0, 0);
        acc1 = __builtin_amdgcn_mfma_f32_16x16x32_bf16(a11, by[1], acc1, 0, 0, 0);

        __builtin_nontemporal_store(acc0 * xv0, (f32x4*)(out + xo0));
        __builtin_nontemporal_store(acc1 * xv1, (f32x4*)(out + xo1));
    }
}

// Fallback if ws_size can't hold the 1MB zt staging (correct but slow).
__global__ __launch_bounds__(256) void sddmm_naive(const float* __restrict__ x,
                                                   const float* __restrict__ y,
                                                   const float* __restrict__ z,
                                                   float* __restrict__ out) {
    size_t i = (size_t)blockIdx.x * 256 + threadIdx.x;
    size_t total = (size_t)M_DIM * N_DIM;
    for (; i < total; i += (size_t)gridDim.x * 256) {
        int m = (int)(i / N_DIM);
        int n = (int)(i % N_DIM);
        float acc = 0.f;
        for (int k = 0; k < K_DIM; ++k)
            acc += y[(size_t)m * K_DIM + k] * z[(size_t)k * N_DIM + n];
        out[i] = x[i] * acc;
    }
}

extern "C" void kernel_launch(void* const* d_in, const int* in_sizes, int n_in,
                              void* d_out, int out_size, void* d_ws, size_t ws_size,
                              hipStream_t stream) {
    const float* x = (const float*)d_in[0];
    const float* y = (const float*)d_in[1];
    const float* z = (const float*)d_in[2];
    float* out = (float*)d_out;

    size_t need = (size_t)N_DIM * K_DIM * sizeof(ushort);   // zt: 1 MB
    if (ws_size < need) {
        sddmm_naive<<<32768, 256, 0, stream>>>(x, y, z, out);
        return;
    }
    ushort* zt = (ushort*)d_ws;

    prep_zt<<<N_DIM / 64, 256, 0, stream>>>(z, zt);   // ~5 us, L2-resident out

    dim3 grid(N_DIM / BLOCK_N, M_DIM / PANEL_M);      // (8, 512)
    sddmm_rows<<<grid, 256, 0, stream>>>(x, y, zt, out);
}